// Round 6
// baseline (349.840 us; speedup 1.0000x reference)
//
#include <hip/hip_runtime.h>
#include <hip/hip_bf16.h>
#include <cmath>

// GAT layer.  B=4, N=2047 (+1 prior node), I=256, O=128, H=4.
// exp(leakyrelu(s_src[i]+s_dst[j])) factorizes per branch:
//   sj >= -si :  e^{si} * e^{sj}          sj < -si :  e^{0.2 si} * e^{0.2 sj}
// Bucket j by s_dst into 256 value-bins (counting sort), per-bin pos/neg sums
// over 128 channels + a "ones" channel (softmax denom), prefix/suffix over
// bins; each output row = 2 prefix-row lookups + boundary-bin members tested
// element-wise.  O(N^2*O) -> O(N*O).
//
// Input dtype (fp32 vs bf16) and mask dtype (u8 vs i32) are detected at
// runtime by k0_detect: fp32 tensors read as u16 streams have ~12.5% entries
// with exponent >= 0xC0 (|v|>=2^65); genuine bf16 data has none.
// kernel_launch contains ONLY kernel launches (no runtime API calls) for
// maximum graph-capture safety; colsum zeroing is folded into k0_detect.

#define B_ 4
#define N_ 2047
#define N1 2048
#define I_ 256
#define O_ 128
#define H_ 4
#define NBINS 256
#define STR 132           // padded row stride for [bin][129] arrays
#define SLOPEC 0.2f

typedef unsigned short u16;
typedef unsigned char u8;

__device__ __forceinline__ float bf2f(u16 v){
  union { unsigned u; float f; } x; x.u = ((unsigned)v) << 16; return x.f;
}
__device__ __forceinline__ u16 f2bf(float f){
  union { float f; unsigned u; } x; x.f = f;
  unsigned u = x.u;
  return (u16)((u + 0x7FFFu + ((u >> 16) & 1u)) >> 16);
}
// dtype-dispatched load (bf = 1 -> bf16, 0 -> fp32); branch is wave-uniform
__device__ __forceinline__ float ldv(const void* p, int bf, size_t i){
  if (bf) return bf2f(reinterpret_cast<const u16*>(p)[i]);
  return reinterpret_cast<const float*>(p)[i];
}
// NaN-laundering clamps (never bind on sane values)
__device__ __forceinline__ float clS(float v){ return fminf(30.f, fmaxf(-30.f, v)); }
__device__ __forceinline__ float clH(float v){ return fminf(1e4f, fmaxf(-1e4f, v)); }
// Monotone binning (same fn for bucketing and queries)
__device__ __forceinline__ int binOf(float v, float lo, float inv){
  int c = (int)((v - lo) * inv);
  c = c < 0 ? 0 : c;
  c = c > NBINS - 1 ? NBINS - 1 : c;
  return c;
}
__device__ __forceinline__ int rdmask(const u8* m, int mode, int idx){
  return mode ? (m[idx] != 0) : (((const int*)m)[idx] != 0);
}

// flags: [0]=mask-is-u8, [1]=x bf16, [2]=prior, [3]=Wlin, [4]=w_head,
//        [5]=a_src, [6]=a_dst   (bias: all zeros, decodes 0 either way -> use [1])
// Also zeroes colsum (512 floats) so kernel_launch needs no hipMemsetAsync.
__global__ __launch_bounds__(256) void k0_detect(const u8* __restrict__ mask,
                                                 const void* x, const void* prior,
                                                 const void* Wlin, const void* wh,
                                                 const void* asr, const void* ads,
                                                 int* __restrict__ flags,
                                                 float* __restrict__ colsum){
  __shared__ int c[8];
  const int t = threadIdx.x;
  for (int i = t; i < B_ * H_ * O_; i += 256) colsum[i] = 0.f;
  if (t < 8) c[t] = 0;
  __syncthreads();
  int local = 0;
  for (int i = t; i < B_ * N1; i += 256)
    if ((i & 3) && mask[i]) local = 1;          // int32 0/1 -> bytes i%4!=0 all zero
  if (local) atomicOr(&c[0], 1);
  const void* ptrs[6] = {x, prior, Wlin, wh, asr, ads};
  const int   lens[6] = {4096, 512, 4096, 4096, 512, 512};  // u16 scan counts (safe both dtypes)
  for (int k = 0; k < 6; k++){
    const u16* p = (const u16*)ptrs[k];
    int g = 0;
    for (int i = t; i < lens[k]; i += 256){
      int e = (p[i] >> 7) & 0xFF;
      if (e >= 0xC0) g++;
    }
    if (g) atomicAdd(&c[k + 1], g);
  }
  __syncthreads();
  if (t == 0) flags[0] = c[0];
  else if (t <= 6) flags[t] = (c[t] < 4) ? 1 : 0;   // 0 garbage hits => bf16
}

// ---------------- K1: hp[b,n,o] = sum_i x[b,n,i]*Wlin[o,i];  row 2047 = prior ----
#define K1_NT 16
__global__ __launch_bounds__(128) void k1_hp(const void* __restrict__ x,
                                             const void* __restrict__ prior,
                                             const void* __restrict__ Wlin,
                                             const int* __restrict__ flags,
                                             float* __restrict__ hp){
  __shared__ float xs[K1_NT][I_];          // 16 KB
  const int fx = flags[1], fp = flags[2], fw = flags[3];
  const int tile = blockIdx.x & (N1 / K1_NT - 1);
  const int b    = blockIdx.x / (N1 / K1_NT);
  const int n0   = tile * K1_NT;
  const int t    = threadIdx.x;            // 128
  for (int r = 0; r < K1_NT; r++){
    int n = n0 + r;
    for (int k = t; k < I_; k += 128)
      xs[r][k] = (n < N_) ? ldv(x, fx, ((size_t)b * N_ + n) * I_ + k) : 0.f;
  }
  __syncthreads();
  const int o = t;
  float acc[K1_NT];
#pragma unroll
  for (int r = 0; r < K1_NT; r++) acc[r] = 0.f;
  for (int i4 = 0; i4 < I_ / 4; i4++){
    const int i = i4 * 4;
    const size_t wb = (size_t)o * I_ + i;
    float w0 = ldv(Wlin, fw, wb), w1 = ldv(Wlin, fw, wb + 1);
    float w2 = ldv(Wlin, fw, wb + 2), w3 = ldv(Wlin, fw, wb + 3);
#pragma unroll
    for (int r = 0; r < K1_NT; r++)
      acc[r] += xs[r][i] * w0 + xs[r][i + 1] * w1 + xs[r][i + 2] * w2 + xs[r][i + 3] * w3;
  }
  const float pv = ldv(prior, fp, b * O_ + o);
  for (int r = 0; r < K1_NT; r++){
    int n = n0 + r;
    hp[((size_t)b * N1 + n) * O_ + o] = (n < N_) ? acc[r] : pv;
  }
}

// ---------------- K2: hph = hp @ w_head[h]; s_src/s_dst; colsum ----
#define K2_NT 8
__global__ __launch_bounds__(128) void k2_heads(const float* __restrict__ hp,
                                                const void* __restrict__ w_head,
                                                const void* __restrict__ a_src,
                                                const void* __restrict__ a_dst,
                                                const int* __restrict__ flags,
                                                float* __restrict__ hph,
                                                float* __restrict__ s_src,
                                                float* __restrict__ s_dst,
                                                float* __restrict__ colsum){
  __shared__ float ws[32][O_];             // 16 KB (K-tile of w_head, fp32)
  __shared__ float hs[K2_NT][O_];          // 4 KB
  __shared__ float red[4];
  const int fw = flags[4], fas = flags[5], fad = flags[6];
  const int ntile = N1 / K2_NT;
  const int tile  = blockIdx.x % ntile;
  const int h     = (blockIdx.x / ntile) % H_;
  const int b     = blockIdx.x / (ntile * H_);
  const int t     = threadIdx.x;           // 128
  const int n0 = tile * K2_NT;
  for (int r = 0; r < K2_NT; r++)
    hs[r][t] = hp[((size_t)b * N1 + n0 + r) * O_ + t];
  const int p = t;
  float acc[K2_NT];
#pragma unroll
  for (int r = 0; r < K2_NT; r++) acc[r] = 0.f;
  for (int ot = 0; ot < O_; ot += 32){
    if (ot) __syncthreads();
    for (int k = t; k < 32 * O_; k += 128)
      ws[k >> 7][k & 127] = ldv(w_head, fw, (size_t)h * O_ * O_ + ((size_t)ot << 7) + k);
    __syncthreads();
#pragma unroll
    for (int oo = 0; oo < 32; oo++){
      const float wv = ws[oo][p];
#pragma unroll
      for (int r = 0; r < K2_NT; r++) acc[r] += hs[r][ot + oo] * wv;
    }
  }
  const int bh = b * H_ + h;
  const float asv = ldv(a_src, fas, h * O_ + p);
  const float adv = ldv(a_dst, fad, h * O_ + p);
  const int wid = t >> 6, lane = t & 63;
  float csum = 0.f;
  for (int r = 0; r < K2_NT; r++){
    const int n = n0 + r;
    float v = clH(acc[r]);
    hph[((size_t)bh * N1 + n) * O_ + p] = v;
    csum += v;
    float tv = tanhf(v);
    float cs = tv * asv, cd = tv * adv;
#pragma unroll
    for (int sft = 32; sft > 0; sft >>= 1){ cs += __shfl_down(cs, sft); cd += __shfl_down(cd, sft); }
    if (lane == 0){ red[wid] = cs; red[2 + wid] = cd; }
    __syncthreads();
    if (t == 0){
      s_src[(size_t)bh * N1 + n] = red[0] + red[1];
      s_dst[(size_t)bh * N1 + n] = red[2] + red[3];
    }
    __syncthreads();
  }
  atomicAdd(&colsum[bh * O_ + p], csum);
}

// ---------------- K2b: min/max of s_dst over unmasked j -> bin range ----
__global__ __launch_bounds__(256) void k2b_range(const float* __restrict__ s_dst,
                                                 const u8* __restrict__ mask,
                                                 const int* __restrict__ flags,
                                                 float* __restrict__ sdlo,
                                                 float* __restrict__ sdinv){
  __shared__ float smn[4], smx[4];
  const int bh = blockIdx.x, b = bh / H_, t = threadIdx.x;
  const int md = flags[0];
  float mn = 3e38f, mx = -3e38f;
  for (int j = t; j < N1; j += 256){
    if (!rdmask(mask, md, b * N1 + j)){
      float v = clS(s_dst[(size_t)bh * N1 + j]);
      mn = fminf(mn, v); mx = fmaxf(mx, v);
    }
  }
#pragma unroll
  for (int sft = 32; sft > 0; sft >>= 1){
    mn = fminf(mn, __shfl_down(mn, sft));
    mx = fmaxf(mx, __shfl_down(mx, sft));
  }
  if ((t & 63) == 0){ smn[t >> 6] = mn; smx[t >> 6] = mx; }
  __syncthreads();
  if (t == 0){
    mn = fminf(fminf(smn[0], smn[1]), fminf(smn[2], smn[3]));
    mx = fmaxf(fmaxf(smx[0], smx[1]), fmaxf(smx[2], smx[3]));
    float range = mx - mn;
    if (!(range > 1e-30f)) range = 1.f;
    sdlo[bh]  = mn;
    sdinv[bh] = (float)NBINS / range;
  }
}

// ---------------- K3a: counting sort of unmasked j by bin ----
__global__ __launch_bounds__(256) void k3a_bucket(const float* __restrict__ s_dst,
                                                  const u8* __restrict__ mask,
                                                  const int* __restrict__ flags,
                                                  const float* __restrict__ sdlo,
                                                  const float* __restrict__ sdinv,
                                                  int* __restrict__ binStart,
                                                  int* __restrict__ order){
  __shared__ int cnt[NBINS];
  __shared__ int part[256];
  __shared__ int offs[NBINS];
  const int bh = blockIdx.x, b = bh / H_, t = threadIdx.x;
  const int md = flags[0];
  const float lo = sdlo[bh], inv = sdinv[bh];
  cnt[t] = 0;
  __syncthreads();
  for (int j = t; j < N1; j += 256){
    if (!rdmask(mask, md, b * N1 + j))
      atomicAdd(&cnt[binOf(clS(s_dst[(size_t)bh * N1 + j]), lo, inv)], 1);
  }
  __syncthreads();
  const int mysum = cnt[t];
  part[t] = mysum;
  __syncthreads();
  for (int off = 1; off < 256; off <<= 1){
    int v = (t >= off) ? part[t - off] : 0;
    __syncthreads();
    part[t] += v;
    __syncthreads();
  }
  const int excl = part[t] - mysum;
  offs[t] = excl;
  binStart[bh * (NBINS + 1) + t] = excl;
  if (t == 255) binStart[bh * (NBINS + 1) + NBINS] = part[255];   // = U
  __syncthreads();
  for (int j = t; j < N1; j += 256){
    if (!rdmask(mask, md, b * N1 + j)){
      int bin = binOf(clS(s_dst[(size_t)bh * N1 + j]), lo, inv);
      int pos = atomicAdd(&offs[bin], 1);
      order[(size_t)bh * N1 + pos] = j;
    }
  }
}

// ---------------- K3b: per-bin sums  (channel 128 = ones, softmax denom) ----
__global__ __launch_bounds__(192) void k3b_binsum(const float* __restrict__ hph,
                                                  const float* __restrict__ s_dst,
                                                  const int* __restrict__ binStart,
                                                  const int* __restrict__ order,
                                                  float* __restrict__ binPos,
                                                  float* __restrict__ binNeg){
  const int gb = blockIdx.x;
  const int bh = gb / NBINS, bin = gb % NBINS;
  const int t = threadIdx.x;
  const int s = binStart[bh * (NBINS + 1) + bin];
  const int e = binStart[bh * (NBINS + 1) + bin + 1];
  float ap = 0.f, an = 0.f;
  for (int m = s; m < e; m++){
    const int j = order[(size_t)bh * N1 + m];
    const float sdj = clS(s_dst[(size_t)bh * N1 + j]);
    const float fp = __expf(sdj), fn = __expf(SLOPEC * sdj);
    const float v = (t < O_) ? hph[((size_t)bh * N1 + j) * O_ + t] : 1.f;
    ap += fp * v; an += fn * v;
  }
  if (t <= O_){
    const size_t basei = ((size_t)bh * NBINS + bin) * STR;
    binPos[basei + t] = ap;
    binNeg[basei + t] = an;
  }
}

// ---------------- K3c: prefix (neg, exclusive) / suffix (pos, inclusive) ----
__global__ __launch_bounds__(64) void k3c_prefix(const float* __restrict__ binPos,
                                                 const float* __restrict__ binNeg,
                                                 float* __restrict__ sufPos,
                                                 float* __restrict__ preNeg){
  const int idx = blockIdx.x * 64 + threadIdx.x;
  if (idx >= 2 * B_ * H_ * 129) return;
  const int ch  = idx % 129;
  const int g   = idx / 129;
  const int bh  = g % (B_ * H_);
  const int arr = g / (B_ * H_);
  if (arr == 0){
    float acc = 0.f;
    for (int r = 0; r < NBINS; r++){
      preNeg[((size_t)bh * (NBINS + 1) + r) * STR + ch] = acc;
      acc += binNeg[((size_t)bh * NBINS + r) * STR + ch];
    }
    preNeg[((size_t)bh * (NBINS + 1) + NBINS) * STR + ch] = acc;
  } else {
    float acc = 0.f;
    sufPos[((size_t)bh * (NBINS + 1) + NBINS) * STR + ch] = 0.f;
    for (int r = NBINS - 1; r >= 0; r--){
      acc += binPos[((size_t)bh * NBINS + r) * STR + ch];
      sufPos[((size_t)bh * (NBINS + 1) + r) * STR + ch] = acc;
    }
  }
}

// ---------------- K3d: output rows ----
__global__ __launch_bounds__(128) void k3d_out(const float* __restrict__ hph,
                                               const float* __restrict__ s_src,
                                               const float* __restrict__ s_dst,
                                               const u8* __restrict__ mask,
                                               const int* __restrict__ flags,
                                               const float* __restrict__ sdlo,
                                               const float* __restrict__ sdinv,
                                               const int* __restrict__ binStart,
                                               const int* __restrict__ order,
                                               const float* __restrict__ sufPos,
                                               const float* __restrict__ preNeg,
                                               const float* __restrict__ colsum,
                                               const void* __restrict__ bias,
                                               void* __restrict__ outp){
  const int blk = blockIdx.x;
  const int b = blk / N1, i = blk % N1, o = threadIdx.x;   // 128 threads
  const int md = flags[0], fo = flags[1];
  const bool mrow = rdmask(mask, md, b * N1 + i) != 0;
  float acc = 0.f;
  for (int h = 0; h < H_; h++){
    const int bh = b * H_ + h;
    const int U = binStart[bh * (NBINS + 1) + NBINS];
    if (mrow || U == 0){
      acc += colsum[bh * O_ + o] * (1.f / N1);   // uniform softmax over all 2048
      continue;
    }
    const float si = clS(s_src[(size_t)bh * N1 + i]);
    const float tthr = -si;
    const int c = binOf(tthr, sdlo[bh], sdinv[bh]);
    const size_t rowp = ((size_t)bh * (NBINS + 1) + c + 1) * STR;  // bins > c
    const size_t rown = ((size_t)bh * (NBINS + 1) + c) * STR;      // bins < c
    float posV = sufPos[rowp + o], posS = sufPos[rowp + O_];
    float negV = preNeg[rown + o], negS = preNeg[rown + O_];
    const int s0 = binStart[bh * (NBINS + 1) + c];
    const int e0 = binStart[bh * (NBINS + 1) + c + 1];
    for (int m = s0; m < e0; m++){       // boundary bin: exact per-element test
      const int j = order[(size_t)bh * N1 + m];
      const float sdj = clS(s_dst[(size_t)bh * N1 + j]);
      const float hv = hph[((size_t)bh * N1 + j) * O_ + o];
      if (sdj >= tthr){ const float fp = __expf(sdj);          posV += fp * hv; posS += fp; }
      else            { const float fn = __expf(SLOPEC * sdj); negV += fn * hv; negS += fn; }
    }
    const float esi = __expf(si), esi2 = __expf(SLOPEC * si);
    const float den = fmaxf(esi * posS + esi2 * negS, 1e-35f);
    acc += (esi * posV + esi2 * negV) / den;
  }
  const float bv = ldv(bias, fo, o);
  const float v = 0.25f * acc + bv;
  const size_t oidx = ((size_t)b * N1 + i) * O_ + o;
  if (fo) ((u16*)outp)[oidx] = f2bf(v);
  else    ((float*)outp)[oidx] = v;
}

extern "C" void kernel_launch(void* const* d_in, const int* in_sizes, int n_in,
                              void* d_out, int out_size, void* d_ws, size_t ws_size,
                              hipStream_t stream){
  const void* x      = d_in[0];
  const void* prior  = d_in[1];
  const u8*   mask   = (const u8*)d_in[2];
  const void* Wlin   = d_in[3];
  const void* w_head = d_in[4];
  const void* a_src  = d_in[5];
  const void* a_dst  = d_in[6];
  const void* bias   = d_in[7];

  char* basep = (char*)d_ws;
  size_t off = 0;
  auto alloc = [&](size_t bytes) -> void* {
    off = (off + 255) & ~(size_t)255;
    void* p = basep + off;
    off += bytes;
    return p;
  };
  int*   flags    = (int*)alloc(32);
  float* hp       = (float*)alloc((size_t)B_ * N1 * O_ * 4);           // 4 MB
  float* hph      = (float*)alloc((size_t)B_ * H_ * N1 * O_ * 4);      // 16 MB
  float* s_src    = (float*)alloc((size_t)B_ * H_ * N1 * 4);
  float* s_dst    = (float*)alloc((size_t)B_ * H_ * N1 * 4);
  float* sdlo     = (float*)alloc(B_ * H_ * 4);
  float* sdinv    = (float*)alloc(B_ * H_ * 4);
  float* colsum   = (float*)alloc((size_t)B_ * H_ * O_ * 4);
  int*   binStart = (int*)alloc((size_t)B_ * H_ * (NBINS + 1) * 4);
  int*   order    = (int*)alloc((size_t)B_ * H_ * N1 * 4);
  float* binPos   = (float*)alloc((size_t)B_ * H_ * NBINS * STR * 4);  // 2.2 MB
  float* binNeg   = (float*)alloc((size_t)B_ * H_ * NBINS * STR * 4);
  float* sufPos   = (float*)alloc((size_t)B_ * H_ * (NBINS + 1) * STR * 4);
  float* preNeg   = (float*)alloc((size_t)B_ * H_ * (NBINS + 1) * STR * 4);
  (void)in_sizes; (void)n_in; (void)out_size; (void)ws_size;           // ~29.3 MB used

  hipLaunchKernelGGL(k0_detect,  dim3(1),   dim3(256), 0, stream, mask, x, prior, Wlin, w_head, a_src, a_dst, flags, colsum);
  hipLaunchKernelGGL(k1_hp,      dim3(B_ * (N1 / K1_NT)),      dim3(128), 0, stream, x, prior, Wlin, flags, hp);
  hipLaunchKernelGGL(k2_heads,   dim3(B_ * H_ * (N1 / K2_NT)), dim3(128), 0, stream, hp, w_head, a_src, a_dst, flags, hph, s_src, s_dst, colsum);
  hipLaunchKernelGGL(k2b_range,  dim3(B_ * H_),                dim3(256), 0, stream, s_dst, mask, flags, sdlo, sdinv);
  hipLaunchKernelGGL(k3a_bucket, dim3(B_ * H_),                dim3(256), 0, stream, s_dst, mask, flags, sdlo, sdinv, binStart, order);
  hipLaunchKernelGGL(k3b_binsum, dim3(B_ * H_ * NBINS),        dim3(192), 0, stream, hph, s_dst, binStart, order, binPos, binNeg);
  hipLaunchKernelGGL(k3c_prefix, dim3((2 * B_ * H_ * 129 + 63) / 64), dim3(64), 0, stream, binPos, binNeg, sufPos, preNeg);
  hipLaunchKernelGGL(k3d_out,    dim3(B_ * N1),                dim3(128), 0, stream, hph, s_src, s_dst, mask, flags, sdlo, sdinv, binStart, order, sufPos, preNeg, colsum, bias, d_out);
}